// Round 1
// baseline (332.950 us; speedup 1.0000x reference)
//
#include <hip/hip_runtime.h>
#include <math.h>

#define N_EL 4096
#define N_NB 32
#define F_IN 5
#define EDGE_FEAT 32
#define FEAT 256
#define CUTOFF 3.0f

// One block per particle n; thread t owns output feature column d = t.
// Gamma[n,k,d] = env[k] * ( sum_f feats[k,f] * FK2[f,d] + FB2[d] )
//   where FK2 = filter_kernel[n] @ W_gamma  (computed per-thread in regs)
//         FB2 = filter_bias[n]   @ W_gamma
// edge[n,k,d] = sum_f feats[k,f] * edge_kernel[n,f,d] + edge_bias[n,d]
__global__ __launch_bounds__(256) void EdgeFeatures_kernel(
    const float* __restrict__ r,            // [N,3]
    const float* __restrict__ r_nb,         // [N,K,3]
    const float* __restrict__ filter_kernel,// [N,5,32]
    const float* __restrict__ filter_bias,  // [N,32]
    const float* __restrict__ W_gamma,      // [32,256]
    const float* __restrict__ edge_kernel_w,// [N,5,256]
    const float* __restrict__ edge_bias,    // [N,256]
    const int*   __restrict__ s,            // [N]
    const int*   __restrict__ s_nb,         // [N,K]
    float*       __restrict__ out)          // Gamma [N,K,256] ++ edge [N,K,256]
{
    const int n = blockIdx.x;
    const int t = threadIdx.x;

    // feats padded to 8 floats per neighbor: dx,dy,dz,dist,same,env,0,0
    __shared__ __align__(16) float lds[N_NB * 8];

    if (t < N_NB) {
        const int k = t;
        const float rx = r[n * 3 + 0], ry = r[n * 3 + 1], rz = r[n * 3 + 2];
        const float* rb = r_nb + ((size_t)n * N_NB + k) * 3;
        const float dx = rb[0] - rx, dy = rb[1] - ry, dz = rb[2] - rz;
        const float dist = sqrtf(dx * dx + dy * dy + dz * dz);
        const float same = (s[n] == s_nb[n * N_NB + k]) ? 1.0f : 0.0f;
        float x = dist * (1.0f / CUTOFF);
        x = fminf(x, 1.0f);                       // dist >= 0 so no lower clip needed
        const float env = (dist < CUTOFF)
                              ? 0.5f * (cosf(3.14159265358979323846f * x) + 1.0f)
                              : 0.0f;
        lds[k * 8 + 0] = dx;
        lds[k * 8 + 1] = dy;
        lds[k * 8 + 2] = dz;
        lds[k * 8 + 3] = dist;
        lds[k * 8 + 4] = same;
        lds[k * 8 + 5] = env;
        lds[k * 8 + 6] = 0.0f;
        lds[k * 8 + 7] = 0.0f;
    }

    // ---- per-thread FK2 column: g[f] = sum_e filter_kernel[n,f,e] * W_gamma[e,t]
    const float* fk = filter_kernel + (size_t)n * F_IN * EDGE_FEAT;  // wave-uniform
    const float* fb = filter_bias + (size_t)n * EDGE_FEAT;           // wave-uniform
    float g0 = 0.f, g1 = 0.f, g2 = 0.f, g3 = 0.f, g4 = 0.f, gb = 0.f;
#pragma unroll
    for (int e = 0; e < EDGE_FEAT; ++e) {
        const float w = W_gamma[e * FEAT + t];  // coalesced, L2-resident
        g0 += fk[0 * EDGE_FEAT + e] * w;
        g1 += fk[1 * EDGE_FEAT + e] * w;
        g2 += fk[2 * EDGE_FEAT + e] * w;
        g3 += fk[3 * EDGE_FEAT + e] * w;
        g4 += fk[4 * EDGE_FEAT + e] * w;
        gb += fb[e] * w;
    }

    // ---- edge projection column, reused across all 32 neighbors
    const float* ek = edge_kernel_w + (size_t)n * F_IN * FEAT;
    const float e0 = ek[0 * FEAT + t];
    const float e1 = ek[1 * FEAT + t];
    const float e2 = ek[2 * FEAT + t];
    const float e3 = ek[3 * FEAT + t];
    const float e4 = ek[4 * FEAT + t];
    const float ebias = edge_bias[(size_t)n * FEAT + t];

    __syncthreads();

    float* outG = out + ((size_t)n * N_NB) * FEAT + t;
    float* outE = out + (size_t)N_EL * N_NB * FEAT + ((size_t)n * N_NB) * FEAT + t;

#pragma unroll 4
    for (int k = 0; k < N_NB; ++k) {
        const float4 v = *reinterpret_cast<const float4*>(&lds[k * 8]);      // dx,dy,dz,dist
        const float2 v2 = *reinterpret_cast<const float2*>(&lds[k * 8 + 4]); // same,env
        float gamma = gb + g0 * v.x + g1 * v.y + g2 * v.z + g3 * v.w + g4 * v2.x;
        gamma *= v2.y;
        const float edge = ebias + e0 * v.x + e1 * v.y + e2 * v.z + e3 * v.w + e4 * v2.x;
        outG[(size_t)k * FEAT] = gamma;
        outE[(size_t)k * FEAT] = edge;
    }
}

extern "C" void kernel_launch(void* const* d_in, const int* in_sizes, int n_in,
                              void* d_out, int out_size, void* d_ws, size_t ws_size,
                              hipStream_t stream) {
    const float* r             = (const float*)d_in[0];
    const float* r_nb          = (const float*)d_in[1];
    const float* filter_kernel = (const float*)d_in[2];
    const float* filter_bias   = (const float*)d_in[3];
    const float* W_gamma       = (const float*)d_in[4];
    const float* edge_kernel_w = (const float*)d_in[5];
    const float* edge_bias     = (const float*)d_in[6];
    const int*   s             = (const int*)d_in[7];
    const int*   s_nb          = (const int*)d_in[8];
    float* out = (float*)d_out;

    EdgeFeatures_kernel<<<N_EL, FEAT, 0, stream>>>(
        r, r_nb, filter_kernel, filter_bias, W_gamma, edge_kernel_w, edge_bias,
        s, s_nb, out);
}

// Round 2
// 329.167 us; speedup vs baseline: 1.0115x; 1.0115x over previous
//
#include <hip/hip_runtime.h>
#include <math.h>

#define N_EL 4096
#define N_NB 32
#define F_IN 5
#define EDGE_FEAT 32
#define FEAT 256
#define CUTOFF 3.0f

// One block per particle n. Thread t = (kg, dv): dv = t&63 owns feature cols
// [4*dv, 4*dv+4); kg = t>>6 owns neighbors [8*kg, 8*kg+8).
// Gamma[n,k,d] = env[k] * ( sum_f feats[k,f] * FK2[f,d] + FB2[d] )
//   FK2 = filter_kernel[n] @ W_gamma (5x FLOP reduction vs reference order),
//   computed once per column (phase 1b), staged via LDS, re-read as float4.
// edge[n,k,d] = sum_f feats[k,f] * edge_kernel[n,f,d] + edge_bias[n,d]
// All global stores are dwordx4 (16 B/lane, 1024 B/wave-instr).
__global__ __launch_bounds__(256) void EdgeFeatures_kernel(
    const float* __restrict__ r,            // [N,3]
    const float* __restrict__ r_nb,         // [N,K,3]
    const float* __restrict__ filter_kernel,// [N,5,32]
    const float* __restrict__ filter_bias,  // [N,32]
    const float* __restrict__ W_gamma,      // [32,256]
    const float* __restrict__ edge_kernel_w,// [N,5,256]
    const float* __restrict__ edge_bias,    // [N,256]
    const int*   __restrict__ s,            // [N]
    const int*   __restrict__ s_nb,         // [N,K]
    float*       __restrict__ out)          // Gamma [N,K,256] ++ edge [N,K,256]
{
    const int n = blockIdx.x;
    const int t = threadIdx.x;

    // feats padded to 8 floats/neighbor: dx,dy,dz,dist,same,env,0,0
    __shared__ __align__(16) float feats[N_NB * 8];
    // FK2 columns + bias: rows 0..4 = g_f, row 5 = bias  -> [6][256]
    __shared__ __align__(16) float fk2[6 * FEAT];

    // ---- phase 1: per-neighbor geometric features (lanes 0..31)
    if (t < N_NB) {
        const int k = t;
        const float rx = r[n * 3 + 0], ry = r[n * 3 + 1], rz = r[n * 3 + 2];
        const float* rb = r_nb + ((size_t)n * N_NB + k) * 3;
        const float dx = rb[0] - rx, dy = rb[1] - ry, dz = rb[2] - rz;
        const float dist = sqrtf(dx * dx + dy * dy + dz * dz);
        const float same = (s[n] == s_nb[n * N_NB + k]) ? 1.0f : 0.0f;
        float x = fminf(dist * (1.0f / CUTOFF), 1.0f);
        const float env = (dist < CUTOFF)
                              ? 0.5f * (cosf(3.14159265358979323846f * x) + 1.0f)
                              : 0.0f;
        feats[k * 8 + 0] = dx;
        feats[k * 8 + 1] = dy;
        feats[k * 8 + 2] = dz;
        feats[k * 8 + 3] = dist;
        feats[k * 8 + 4] = same;
        feats[k * 8 + 5] = env;
        feats[k * 8 + 6] = 0.0f;
        feats[k * 8 + 7] = 0.0f;
    }

    // ---- phase 1b: FK2 column t (partial unroll to cap VGPR pressure)
    {
        const float* fk = filter_kernel + (size_t)n * F_IN * EDGE_FEAT;  // wave-uniform
        const float* fb = filter_bias + (size_t)n * EDGE_FEAT;           // wave-uniform
        float g0 = 0.f, g1 = 0.f, g2 = 0.f, g3 = 0.f, g4 = 0.f, gb = 0.f;
#pragma unroll 8
        for (int e = 0; e < EDGE_FEAT; ++e) {
            const float w = W_gamma[e * FEAT + t];  // coalesced, L2-resident
            g0 += fk[0 * EDGE_FEAT + e] * w;
            g1 += fk[1 * EDGE_FEAT + e] * w;
            g2 += fk[2 * EDGE_FEAT + e] * w;
            g3 += fk[3 * EDGE_FEAT + e] * w;
            g4 += fk[4 * EDGE_FEAT + e] * w;
            gb += fb[e] * w;
        }
        fk2[0 * FEAT + t] = g0;
        fk2[1 * FEAT + t] = g1;
        fk2[2 * FEAT + t] = g2;
        fk2[3 * FEAT + t] = g3;
        fk2[4 * FEAT + t] = g4;
        fk2[5 * FEAT + t] = gb;
    }

    const int dv = t & 63;
    const int kg = t >> 6;
    const int d0 = dv * 4;

    // ---- edge projection columns (float4), reused across 8 neighbors
    const float* ek = edge_kernel_w + (size_t)n * F_IN * FEAT;
    const float4 E0 = *reinterpret_cast<const float4*>(ek + 0 * FEAT + d0);
    const float4 E1 = *reinterpret_cast<const float4*>(ek + 1 * FEAT + d0);
    const float4 E2 = *reinterpret_cast<const float4*>(ek + 2 * FEAT + d0);
    const float4 E3 = *reinterpret_cast<const float4*>(ek + 3 * FEAT + d0);
    const float4 E4 = *reinterpret_cast<const float4*>(ek + 4 * FEAT + d0);
    const float4 EB = *reinterpret_cast<const float4*>(edge_bias + (size_t)n * FEAT + d0);

    __syncthreads();

    const float4 G0 = *reinterpret_cast<const float4*>(&fk2[0 * FEAT + d0]);
    const float4 G1 = *reinterpret_cast<const float4*>(&fk2[1 * FEAT + d0]);
    const float4 G2 = *reinterpret_cast<const float4*>(&fk2[2 * FEAT + d0]);
    const float4 G3 = *reinterpret_cast<const float4*>(&fk2[3 * FEAT + d0]);
    const float4 G4 = *reinterpret_cast<const float4*>(&fk2[4 * FEAT + d0]);
    const float4 GB = *reinterpret_cast<const float4*>(&fk2[5 * FEAT + d0]);

    float* baseG = out + ((size_t)n * N_NB) * FEAT + d0;
    float* baseE = baseG + (size_t)N_EL * N_NB * FEAT;

#pragma unroll
    for (int j = 0; j < 8; ++j) {
        const int k = kg * 8 + j;
        const float4 v  = *reinterpret_cast<const float4*>(&feats[k * 8]);     // dx,dy,dz,dist
        const float2 se = *reinterpret_cast<const float2*>(&feats[k * 8 + 4]); // same,env

        float4 gamma, edge;
        gamma.x = (GB.x + G0.x * v.x + G1.x * v.y + G2.x * v.z + G3.x * v.w + G4.x * se.x) * se.y;
        gamma.y = (GB.y + G0.y * v.x + G1.y * v.y + G2.y * v.z + G3.y * v.w + G4.y * se.x) * se.y;
        gamma.z = (GB.z + G0.z * v.x + G1.z * v.y + G2.z * v.z + G3.z * v.w + G4.z * se.x) * se.y;
        gamma.w = (GB.w + G0.w * v.x + G1.w * v.y + G2.w * v.z + G3.w * v.w + G4.w * se.x) * se.y;

        edge.x = EB.x + E0.x * v.x + E1.x * v.y + E2.x * v.z + E3.x * v.w + E4.x * se.x;
        edge.y = EB.y + E0.y * v.x + E1.y * v.y + E2.y * v.z + E3.y * v.w + E4.y * se.x;
        edge.z = EB.z + E0.z * v.x + E1.z * v.y + E2.z * v.z + E3.z * v.w + E4.z * se.x;
        edge.w = EB.w + E0.w * v.x + E1.w * v.y + E2.w * v.z + E3.w * v.w + E4.w * se.x;

        *reinterpret_cast<float4*>(baseG + (size_t)k * FEAT) = gamma;
        *reinterpret_cast<float4*>(baseE + (size_t)k * FEAT) = edge;
    }
}

extern "C" void kernel_launch(void* const* d_in, const int* in_sizes, int n_in,
                              void* d_out, int out_size, void* d_ws, size_t ws_size,
                              hipStream_t stream) {
    const float* r             = (const float*)d_in[0];
    const float* r_nb          = (const float*)d_in[1];
    const float* filter_kernel = (const float*)d_in[2];
    const float* filter_bias   = (const float*)d_in[3];
    const float* W_gamma       = (const float*)d_in[4];
    const float* edge_kernel_w = (const float*)d_in[5];
    const float* edge_bias     = (const float*)d_in[6];
    const int*   s             = (const int*)d_in[7];
    const int*   s_nb          = (const int*)d_in[8];
    float* out = (float*)d_out;

    EdgeFeatures_kernel<<<N_EL, FEAT, 0, stream>>>(
        r, r_nb, filter_kernel, filter_bias, W_gamma, edge_kernel_w, edge_bias,
        s, s_nb, out);
}